// Round 11
// baseline (3606.994 us; speedup 1.0000x reference)
//
#include <hip/hip_runtime.h>

#define BB 256
#define TT 2048
#define II 64
#define HH 256
#define OO 64
#define FF 16

// ---------------------------------------------------------------------------
// R16: R12 measured: l0 1957us (2293 cyc/step, VALUBusy 42.9% -> 983 busy,
// ~1300 IDLE = 57%), VGPR=88 (zero copy tax -> register theory validated);
// l1 ~1650us. The idle is the [HIP-compiler] barrier drain: __syncthreads()
// emits s_waitcnt vmcnt(0) lgkmcnt(0) before s_barrier, so every step waits
// for the hstream global-store ack (l0) / gi load (l1) with all 8 waves
// stalled together. Fix (single variable): in-loop barriers become raw
//   s_waitcnt lgkmcnt(0); s_barrier      (no vmcnt drain)
// Safe because the LDS dbuf only needs LDS visibility; global ops have no
// intra-kernel consumers (hstream is read by the NEXT kernel; x/gi loads get
// per-thread vmcnt waits at their uses from the compiler).
// Everything else byte-identical to the measured R12 layer-split pipeline.
// ---------------------------------------------------------------------------

typedef _Float16 h2 __attribute__((ext_vector_type(2)));
typedef _Float16 h8 __attribute__((ext_vector_type(8)));

// raw workgroup barrier: order LDS only, leave the VMEM queue in flight
#define BAR_LDS() asm volatile("s_waitcnt lgkmcnt(0)\n\ts_barrier" ::: "memory")

__device__ __forceinline__ float fdot2f(h2 a, h2 b, float c) {
  return __builtin_amdgcn_fdot2(a, b, c, false);  // v_dot2_f32_f16
}
__device__ __forceinline__ h2 i2h(int w) {
  union { int i; h2 h; } u; u.i = w; return u.h;
}
__device__ __forceinline__ int pk2i(const float* p) {
  union { h2 h; int i; } u; u.h[0] = (_Float16)p[0]; u.h[1] = (_Float16)p[1];
  return u.i;
}
__device__ __forceinline__ float fast_tanh(float z) {
  float e = __builtin_amdgcn_exp2f(z * 2.885390081777927f);
  return 1.0f - 2.0f * __builtin_amdgcn_rcpf(e + 1.0f);
}
// 0xB1 quad xor1, 0x4E quad xor2, 0x141 row_half_mirror (kg <-> 7-kg)
template <int CTRL>
__device__ __forceinline__ float dpp_add(float v) {
  union { float f; int i; } a, r;
  a.f = v;
  r.i = __builtin_amdgcn_update_dpp(0, a.i, CTRL, 0xF, 0xF, true);
  return v + r.f;
}

// =================== phase 1: layer 0 ===================
// LDS: h0 dbuf 2x(8 slices x 80B) @0; x dbuf 2x(8 x 16B) @1280. Total 1536 B.
#define P1_HB(i) ((i) * 640)
#define P1_XB(i) (1280 + (i) * 128)

#define L0_STEP(T, RB, WB)                                                     \
  {                                                                            \
    float xn = 0.f;                                                            \
    if ((tid & 7) == 0) {                                                      \
      int tg = tstart + (T) + 1; if (tg > TT - 1) tg = TT - 1;                 \
      xn = xrow[(size_t)tg * II + xi];                                         \
    }                                                                          \
    float aa[4] = {0.f, 0.f, 0.f, 0.f};                                        \
    {                                                                          \
      const int4 xv = *(const int4*)(lb + P1_XB(RB) + kg * 16);                \
      _Pragma("unroll") for (int r = 0; r < 4; ++r) {                          \
        aa[r] = fdot2f(i2h(xv.x), i2h(w0x[r][0]), aa[r]);                      \
        aa[r] = fdot2f(i2h(xv.y), i2h(w0x[r][1]), aa[r]);                      \
        aa[r] = fdot2f(i2h(xv.z), i2h(w0x[r][2]), aa[r]);                      \
        aa[r] = fdot2f(i2h(xv.w), i2h(w0x[r][3]), aa[r]);                      \
      }                                                                        \
    }                                                                          \
    _Pragma("unroll") for (int c = 0; c < 4; ++c) {                            \
      const int4 v = *(const int4*)(lb + P1_HB(RB) + kg * 80 + c * 16);        \
      _Pragma("unroll") for (int r = 0; r < 4; ++r) {                          \
        aa[r] = fdot2f(i2h(v.x), i2h(w0h[r][4 * c + 0]), aa[r]);               \
        aa[r] = fdot2f(i2h(v.y), i2h(w0h[r][4 * c + 1]), aa[r]);               \
        aa[r] = fdot2f(i2h(v.z), i2h(w0h[r][4 * c + 2]), aa[r]);               \
        aa[r] = fdot2f(i2h(v.w), i2h(w0h[r][4 * c + 3]), aa[r]);               \
      }                                                                        \
    }                                                                          \
    _Pragma("unroll") for (int r = 0; r < 4; ++r) {                            \
      aa[r] = dpp_add<0xB1>(aa[r]); aa[r] = dpp_add<0x4E>(aa[r]);              \
      aa[r] = dpp_add<0x141>(aa[r]);                                           \
    }                                                                          \
    float s0 = (kg & 1) ? aa[1] : aa[0];                                       \
    float s1 = (kg & 1) ? aa[3] : aa[2];                                       \
    float hnew = fast_tanh(((kg & 2) ? s1 : s0) + mybias);                     \
    if (kg < 4) {                                                              \
      *(_Float16*)(lb + P1_HB(WB) + (cj >> 5) * 80 + (cj & 31) * 2) =          \
          (_Float16)hnew;                                                      \
      hstream[(bt + (T)) * HH + cj] = (_Float16)hnew;                          \
      if (tstart + (T) == TT - 1) h0keep = hnew;                               \
    }                                                                          \
    if ((tid & 7) == 0)                                                        \
      *(_Float16*)(lb + P1_XB(WB) + (xi >> 3) * 16 + (xi & 7) * 2) =           \
          (_Float16)xn;                                                        \
    BAR_LDS();                                                                 \
  }

__global__ __attribute__((amdgpu_flat_work_group_size(512, 512),
                          amdgpu_waves_per_eu(2, 2)))
void rnn_l0(const float* __restrict__ x, const float* __restrict__ hidden,
            const float* __restrict__ Wih0, const float* __restrict__ Whh0,
            const float* __restrict__ bih0, const float* __restrict__ bhh0,
            _Float16* __restrict__ hstream, float* __restrict__ out,
            int tstart, int tcount)
{
  const int tid = threadIdx.x;
  const int b = blockIdx.x;
  const int kg = tid & 7;            // K-group (8 x-halfs / 32 h-halfs)
  const int r0 = (tid >> 3) * 4;     // first of 4 owned rows
  const int cj = r0 + (kg & 3);      // committed row (lanes kg<4)
  const int xi = tid >> 3;           // x elem for (tid&7)==0 lanes

  __shared__ __align__(16) char lds[1536];
  char* lb = (char*)lds;
  const size_t bt = (size_t)b * tcount;

  // weights: 4 rows x (x:4 + h:16) = 80 ints -> fits the 128-reg arch half
  int w0x[4][4], w0h[4][16];
#pragma unroll
  for (int r = 0; r < 4; ++r) {
    const float* p0 = Wih0 + (size_t)(r0 + r) * II + kg * 8;
#pragma unroll
    for (int m = 0; m < 4; ++m) w0x[r][m] = pk2i(p0 + 2 * m);
    const float* p1 = Whh0 + (size_t)(r0 + r) * HH + kg * 32;
#pragma unroll
    for (int m = 0; m < 16; ++m) w0h[r][m] = pk2i(p1 + 2 * m);
  }
#pragma unroll
  for (int r = 0; r < 4; ++r) {
#pragma unroll
    for (int m = 0; m < 4; ++m) asm volatile("" : "+v"(w0x[r][m]));
#pragma unroll
    for (int m = 0; m < 16; ++m) asm volatile("" : "+v"(w0h[r][m]));
  }
  float mybias = bih0[cj] + bhh0[cj];
  asm volatile("" : "+v"(mybias));

  const float* xrow = x + (size_t)b * TT * II;

  // init: h0 state (chunk0: hidden[0]; else last row of previous stream,
  // still intact since this launch only overwrites during the loop), x row
  if (tid < HH) {
    _Float16 hv = (tstart == 0)
        ? (_Float16)hidden[(size_t)b * HH + tid]
        : hstream[(bt + (tcount - 1)) * HH + tid];
    *(_Float16*)(lb + P1_HB(0) + (tid >> 5) * 80 + (tid & 31) * 2) = hv;
  }
  if (tid < II)
    *(_Float16*)(lb + P1_XB(0) + (tid >> 3) * 16 + (tid & 7) * 2) =
        (_Float16)xrow[(size_t)tstart * II + tid];
  float h0keep = 0.f;
  __syncthreads();

#pragma unroll 1
  for (int t = 0; t < tcount; t += 2) {
    L0_STEP(t, 0, 1)
    L0_STEP(t + 1, 1, 0)
  }

  if (tstart + tcount == TT && kg < 4)
    out[BB * FF * OO + (size_t)b * HH + cj] = h0keep;  // new_hidden[0], f32
}

// =================== phase 2: layer 1 + tail FC ===================
// LDS: h0in dbuf 2x640 @0; h1 dbuf 2x640 @1280; tail FFx512B @2560. 10752 B.
#define P2_GB(i) ((i) * 640)
#define P2_HB(i) (1280 + (i) * 640)
#define P2_TAIL 2560

#define L1_STEP(T, RB, WB)                                                     \
  {                                                                            \
    int gn = 0;                                                                \
    if (tid < 128) {                                                           \
      int tn = (T) + 1; if (tn > tcount - 1) tn = tcount - 1;                  \
      gn = gi[(bt + tn) * 128 + tid];                                          \
    }                                                                          \
    float aa[4] = {0.f, 0.f, 0.f, 0.f};                                        \
    _Pragma("unroll") for (int c = 0; c < 4; ++c) {                            \
      const int4 v = *(const int4*)(lb + P2_GB(RB) + kg * 80 + c * 16);        \
      _Pragma("unroll") for (int r = 0; r < 4; ++r) {                          \
        aa[r] = fdot2f(i2h(v.x), i2h(w1g[r][4 * c + 0]), aa[r]);               \
        aa[r] = fdot2f(i2h(v.y), i2h(w1g[r][4 * c + 1]), aa[r]);               \
        aa[r] = fdot2f(i2h(v.z), i2h(w1g[r][4 * c + 2]), aa[r]);               \
        aa[r] = fdot2f(i2h(v.w), i2h(w1g[r][4 * c + 3]), aa[r]);               \
      }                                                                        \
    }                                                                          \
    _Pragma("unroll") for (int c = 0; c < 4; ++c) {                            \
      const int4 v = *(const int4*)(lb + P2_HB(RB) + kg * 80 + c * 16);        \
      _Pragma("unroll") for (int r = 0; r < 4; ++r) {                          \
        aa[r] = fdot2f(i2h(v.x), i2h(w1h[r][4 * c + 0]), aa[r]);               \
        aa[r] = fdot2f(i2h(v.y), i2h(w1h[r][4 * c + 1]), aa[r]);               \
        aa[r] = fdot2f(i2h(v.z), i2h(w1h[r][4 * c + 2]), aa[r]);               \
        aa[r] = fdot2f(i2h(v.w), i2h(w1h[r][4 * c + 3]), aa[r]);               \
      }                                                                        \
    }                                                                          \
    _Pragma("unroll") for (int r = 0; r < 4; ++r) {                            \
      aa[r] = dpp_add<0xB1>(aa[r]); aa[r] = dpp_add<0x4E>(aa[r]);              \
      aa[r] = dpp_add<0x141>(aa[r]);                                           \
    }                                                                          \
    float s0 = (kg & 1) ? aa[1] : aa[0];                                       \
    float s1 = (kg & 1) ? aa[3] : aa[2];                                       \
    float hnew = fast_tanh(((kg & 2) ? s1 : s0) + mybias);                     \
    if (kg < 4) {                                                              \
      *(_Float16*)(lb + P2_HB(WB) + (cj >> 5) * 80 + (cj & 31) * 2) =          \
          (_Float16)hnew;                                                      \
      if (lastchunk && (T) >= tcount - FF)                                     \
        *(_Float16*)(lb + P2_TAIL + ((T) - (tcount - FF)) * 512 + cj * 2) =    \
            (_Float16)hnew;                                                    \
      if (lastchunk && (T) == tcount - 1) h1keep = hnew;                       \
    }                                                                          \
    if (tid < 128)                                                             \
      *(int*)(lb + P2_GB(WB) + (tid >> 4) * 80 + (tid & 15) * 4) = gn;         \
    BAR_LDS();                                                                 \
  }

__global__ __attribute__((amdgpu_flat_work_group_size(512, 512),
                          amdgpu_waves_per_eu(2, 2)))
void rnn_l1(const float* __restrict__ hidden, const float* __restrict__ Wih1,
            const float* __restrict__ Whh1, const float* __restrict__ bih1,
            const float* __restrict__ bhh1, const float* __restrict__ fcW,
            const float* __restrict__ fcb, const _Float16* __restrict__ hstream,
            _Float16* __restrict__ h1carry, float* __restrict__ out,
            int tstart, int tcount)
{
  const int tid = threadIdx.x;
  const int b = blockIdx.x;
  const int kg = tid & 7;
  const int r0 = (tid >> 3) * 4;
  const int cj = r0 + (kg & 3);
  const bool lastchunk = (tstart + tcount == TT);

  __shared__ __align__(16) char lds[10752];
  char* lb = (char*)lds;
  const size_t bt = (size_t)b * tcount;
  const int* gi = (const int*)hstream;

  // weights: 4 rows x (g:16 + h:16) = 128 ints (~35 spill into AGPR half)
  int w1g[4][16], w1h[4][16];
#pragma unroll
  for (int r = 0; r < 4; ++r) {
    const float* p2 = Wih1 + (size_t)(r0 + r) * HH + kg * 32;
#pragma unroll
    for (int m = 0; m < 16; ++m) w1g[r][m] = pk2i(p2 + 2 * m);
    const float* p3 = Whh1 + (size_t)(r0 + r) * HH + kg * 32;
#pragma unroll
    for (int m = 0; m < 16; ++m) w1h[r][m] = pk2i(p3 + 2 * m);
  }
#pragma unroll
  for (int r = 0; r < 4; ++r) {
#pragma unroll
    for (int m = 0; m < 16; ++m) {
      asm volatile("" : "+v"(w1g[r][m]));
      asm volatile("" : "+v"(w1h[r][m]));
    }
  }
  float mybias = bih1[cj] + bhh1[cj];
  asm volatile("" : "+v"(mybias));

  // init: h1 state (chunk0: hidden[1]; else carry), h0in row 0
  if (tid < HH) {
    _Float16 hv = (tstart == 0)
        ? (_Float16)hidden[(size_t)(BB + b) * HH + tid]
        : h1carry[(size_t)b * HH + tid];
    *(_Float16*)(lb + P2_HB(0) + (tid >> 5) * 80 + (tid & 31) * 2) = hv;
  }
  if (tid < 128)
    *(int*)(lb + P2_GB(0) + (tid >> 4) * 80 + (tid & 15) * 4) = gi[bt * 128 + tid];
  float h1keep = 0.f;
  __syncthreads();

#pragma unroll 1
  for (int t = 0; t < tcount; t += 2) {
    L1_STEP(t, 0, 1)
    L1_STEP(t + 1, 1, 0)
  }

  // carry h1 state (final state is in buffer 0: tcount even)
  if (tid < HH)
    h1carry[(size_t)b * HH + tid] =
        *(_Float16*)(lb + P2_HB(0) + (tid >> 5) * 80 + (tid & 31) * 2);

  if (!lastchunk) return;

  // new_hidden[1], f32-accurate
  if (kg < 4) out[BB * FF * OO + (size_t)(BB + b) * HH + cj] = h1keep;

  __syncthreads();  // tail complete before FC reads

  // out[b,f,o] = tail[f] . fcW[o,:] + fcb[o]
  const int o = tid & 63;
  const int fg = tid >> 6;  // f = 2*fg, 2*fg+1
  const _Float16* tp = (const _Float16*)(lb + P2_TAIL);
  float acc0 = 0.f, acc1 = 0.f;
  const float* wrow = fcW + o * HH;
  for (int c = 0; c < HH / 8; ++c) {
    float wv[8];
#pragma unroll
    for (int k = 0; k < 8; ++k) wv[k] = wrow[8 * c + k];
    h8 q0 = *(const h8*)(tp + (2 * fg) * HH + 8 * c);
    h8 q1 = *(const h8*)(tp + (2 * fg + 1) * HH + 8 * c);
#pragma unroll
    for (int e = 0; e < 8; ++e) {
      acc0 += (float)q0[e] * wv[e];
      acc1 += (float)q1[e] * wv[e];
    }
  }
  const float bo = fcb[o];
  out[((size_t)b * FF + 2 * fg) * OO + o] = acc0 + bo;
  out[((size_t)b * FF + 2 * fg + 1) * OO + o] = acc1 + bo;
}

extern "C" void kernel_launch(void* const* d_in, const int* in_sizes, int n_in,
                              void* d_out, int out_size, void* d_ws, size_t ws_size,
                              hipStream_t stream) {
  (void)in_sizes; (void)n_in; (void)out_size;
  const float* x    = (const float*)d_in[0];
  const float* hid  = (const float*)d_in[1];
  const float* Wih0 = (const float*)d_in[2];
  const float* Whh0 = (const float*)d_in[3];
  const float* bih0 = (const float*)d_in[4];
  const float* bhh0 = (const float*)d_in[5];
  const float* Wih1 = (const float*)d_in[6];
  const float* Whh1 = (const float*)d_in[7];
  const float* bih1 = (const float*)d_in[8];
  const float* bhh1 = (const float*)d_in[9];
  const float* fcW  = (const float*)d_in[10];
  const float* fcb  = (const float*)d_in[11];
  float* out = (float*)d_out;

  // largest even chunk whose h0-stream + h1-carry fits the workspace
  size_t tch = 2048;
  while (tch > 2 &&
         ((size_t)BB * tch * HH * 2 + (size_t)BB * HH * 2) > ws_size)
    tch >>= 1;
  _Float16* hstream = (_Float16*)d_ws;
  _Float16* h1carry = (_Float16*)d_ws + (size_t)BB * tch * HH;

  for (int ts = 0; ts < TT; ts += (int)tch) {
    rnn_l0<<<dim3(BB), dim3(512), 0, stream>>>(
        x, hid, Wih0, Whh0, bih0, bhh0, hstream, out, ts, (int)tch);
    rnn_l1<<<dim3(BB), dim3(512), 0, stream>>>(
        hid, Wih1, Whh1, bih1, bhh1, fcW, fcb, hstream, h1carry, out,
        ts, (int)tch);
  }
}